// Round 1
// baseline (1866.084 us; speedup 1.0000x reference)
//
#include <hip/hip_runtime.h>

#define C 64

// Layout: 16 threads per point, each thread owns 4 channels (float4).
// Kernel 1: gather v_feats row, compute 2-logit gate MLP (16-lane shfl
// reduction), softmax, fused point feature -> write fuse + atomic scatter-add
// into the v_new accumulator region of d_out, count atomics into d_ws.
// Kernel 2: v_new /= max(count,1).

__global__ __launch_bounds__(256) void fuse_scatter_kernel(
    const float* __restrict__ p_feats, const float* __restrict__ v_feats,
    const float* __restrict__ Wp, const float* __restrict__ bp,
    const float* __restrict__ Wv, const float* __restrict__ bv,
    const int* __restrict__ p2v,
    float* __restrict__ fuse_out,   // [n_pts*C]
    float* __restrict__ sums,       // [n_vox*C]  (v_new region of d_out, pre-zeroed)
    int* __restrict__ counts,       // [n_vox]    (d_ws, pre-zeroed)
    int n_pts)
{
    const int t = threadIdx.x & 15;            // thread-within-point (4 channels each)

    // Gate weights: Wp is [C,2] row-major; thread t needs rows 4t..4t+3
    // => flat elements 8t..8t+7 = two float4s with (w0,w1) interleaved.
    const float4* Wp4 = (const float4*)Wp;
    const float4* Wv4 = (const float4*)Wv;
    const float4 wpA = Wp4[2 * t], wpB = Wp4[2 * t + 1];
    const float4 wvA = Wv4[2 * t], wvB = Wv4[2 * t + 1];
    const float bias0 = bp[0] + bv[0];
    const float bias1 = bp[1] + bv[1];

    const int gid = blockIdx.x * blockDim.x + threadIdx.x;
    const int stride = (gridDim.x * blockDim.x) >> 4;

    for (int pt = gid >> 4; pt < n_pts; pt += stride) {
        const int vox = p2v[pt];
        const float4 pf = *(const float4*)(p_feats + (size_t)pt * C + t * 4);
        const float4 vf = *(const float4*)(v_feats + (size_t)vox * C + t * 4);

        float l0 = pf.x * wpA.x + pf.y * wpA.z + pf.z * wpB.x + pf.w * wpB.z
                 + vf.x * wvA.x + vf.y * wvA.z + vf.z * wvB.x + vf.w * wvB.z;
        float l1 = pf.x * wpA.y + pf.y * wpA.w + pf.z * wpB.y + pf.w * wpB.w
                 + vf.x * wvA.y + vf.y * wvA.w + vf.z * wvB.y + vf.w * wvB.w;

        // reduce across the 16 threads of this point (stays inside the group
        // since xor masks < 16 and groups are 16-aligned within the wave)
        #pragma unroll
        for (int m = 1; m < 16; m <<= 1) {
            l0 += __shfl_xor(l0, m);
            l1 += __shfl_xor(l1, m);
        }
        l0 += bias0;
        l1 += bias1;

        const float mx = fmaxf(l0, l1);
        const float e0 = __expf(l0 - mx), e1 = __expf(l1 - mx);
        const float w0 = e0 / (e0 + e1);
        const float w1 = 1.0f - w0;

        float4 f;
        f.x = pf.x * w0 + vf.x * w1;
        f.y = pf.y * w0 + vf.y * w1;
        f.z = pf.z * w0 + vf.z * w1;
        f.w = pf.w * w0 + vf.w * w1;

        *(float4*)(fuse_out + (size_t)pt * C + t * 4) = f;

        float* s = sums + (size_t)vox * C + t * 4;
        atomicAdd(s + 0, f.x);
        atomicAdd(s + 1, f.y);
        atomicAdd(s + 2, f.z);
        atomicAdd(s + 3, f.w);
        if (t == 0) atomicAdd(counts + vox, 1);
    }
}

__global__ __launch_bounds__(256) void divide_kernel(
    float* __restrict__ sums, const int* __restrict__ counts, int n_vox)
{
    const int gid = blockIdx.x * blockDim.x + threadIdx.x;  // one per 4 channels
    const int total = n_vox * (C / 4);
    if (gid >= total) return;
    const int vox = gid >> 4;  // 16 float4-threads per voxel row
    const float inv = 1.0f / (float)max(counts[vox], 1);
    float4* p = (float4*)sums + gid;
    float4 v = *p;
    v.x *= inv; v.y *= inv; v.z *= inv; v.w *= inv;
    *p = v;
}

extern "C" void kernel_launch(void* const* d_in, const int* in_sizes, int n_in,
                              void* d_out, int out_size, void* d_ws, size_t ws_size,
                              hipStream_t stream) {
    const float* p_feats = (const float*)d_in[0];
    const float* v_feats = (const float*)d_in[1];
    const float* Wp = (const float*)d_in[2];
    const float* bp = (const float*)d_in[3];
    const float* Wv = (const float*)d_in[4];
    const float* bv = (const float*)d_in[5];
    const int* p2v = (const int*)d_in[6];

    const int n_pts = in_sizes[0] / C;
    const int n_vox = in_sizes[1] / C;

    float* fuse_out = (float*)d_out;
    float* v_new = fuse_out + (size_t)n_pts * C;   // accumulator lives in d_out
    int* counts = (int*)d_ws;

    // zero accumulators every call (harness does not re-poison between replays)
    hipMemsetAsync(v_new, 0, (size_t)n_vox * C * sizeof(float), stream);
    hipMemsetAsync(counts, 0, (size_t)n_vox * sizeof(int), stream);

    const int threads = 256;
    const int blocks1 = 8192;                      // grid-stride, ~15 pts/group
    fuse_scatter_kernel<<<blocks1, threads, 0, stream>>>(
        p_feats, v_feats, Wp, bp, Wv, bv, p2v, fuse_out, v_new, counts, n_pts);

    const int total2 = n_vox * (C / 4);
    const int blocks2 = (total2 + threads - 1) / threads;
    divide_kernel<<<blocks2, threads, 0, stream>>>(v_new, counts, n_vox);
}

// Round 2
// 671.486 us; speedup vs baseline: 2.7790x; 2.7790x over previous
//
#include <hip/hip_runtime.h>

#define C 64

// ---------------------------------------------------------------------------
// Plan (CSR scatter-mean, no float atomics):
//  1. memset counts
//  2. hist:   counts[v]++ per point           (int atomics, 1.6MB L2-resident)
//  3. scan1:  per-block (2048) reduce -> blockSums
//  4. scan2:  single-block scan of blockSums (nb<=256), offsets[n_vox]=total
//  5. scan3:  per-block exclusive scan -> offsets; cursor=offsets (in place)
//  6. fill:   plist[atomicAdd(cursor[v])] = point_id
//  7. fuse:   gather v_feats, gate MLP + softmax, write fuse (pure streaming)
//  8. gather: per voxel sum fuse rows of its points, divide by count -> v_new
// ---------------------------------------------------------------------------

static const int SCAN_ELEMS = 2048;   // 256 threads x 8

__global__ __launch_bounds__(256) void hist_kernel(
    const int* __restrict__ p2v, int* __restrict__ counts, int n)
{
    int i = blockIdx.x * blockDim.x + threadIdx.x;
    if (i < n) atomicAdd(&counts[p2v[i]], 1);
}

__global__ __launch_bounds__(256) void scan1_kernel(
    const int* __restrict__ counts, int* __restrict__ blockSums, int n)
{
    const int base = blockIdx.x * SCAN_ELEMS;
    const int tid = threadIdx.x;
    int s = 0;
    const int i0 = base + tid * 8;
    #pragma unroll
    for (int j = 0; j < 8; j++) {
        int idx = i0 + j;
        s += (idx < n) ? counts[idx] : 0;
    }
    // wave reduce
    #pragma unroll
    for (int m = 1; m < 64; m <<= 1) s += __shfl_xor(s, m);
    __shared__ int wsum[4];
    const int lane = tid & 63, wave = tid >> 6;
    if (lane == 0) wsum[wave] = s;
    __syncthreads();
    if (tid == 0) blockSums[blockIdx.x] = wsum[0] + wsum[1] + wsum[2] + wsum[3];
}

__global__ __launch_bounds__(256) void scan2_kernel(
    int* __restrict__ blockSums, int* __restrict__ offsets, int nb, int n_vox)
{
    __shared__ int sh[256];
    const int tid = threadIdx.x;
    const int v = (tid < nb) ? blockSums[tid] : 0;
    sh[tid] = v;
    __syncthreads();
    #pragma unroll
    for (int off = 1; off < 256; off <<= 1) {
        int t = (tid >= off) ? sh[tid - off] : 0;
        __syncthreads();
        sh[tid] += t;
        __syncthreads();
    }
    if (tid < nb) blockSums[tid] = sh[tid] - v;   // exclusive
    if (tid == 255) offsets[n_vox] = sh[255];     // total = n_pts
}

__global__ __launch_bounds__(256) void scan3_kernel(
    const int* __restrict__ counts, const int* __restrict__ blockSums,
    int* __restrict__ offsets, int* __restrict__ cursor, int n)
{
    const int base = blockIdx.x * SCAN_ELEMS;
    const int tid = threadIdx.x;
    const int i0 = base + tid * 8;
    int vals[8];
    #pragma unroll
    for (int j = 0; j < 8; j++) {
        int idx = i0 + j;
        vals[j] = (idx < n) ? counts[idx] : 0;
    }
    int s = 0;
    #pragma unroll
    for (int j = 0; j < 8; j++) s += vals[j];

    const int lane = tid & 63, wave = tid >> 6;
    int incl = s;
    #pragma unroll
    for (int off = 1; off < 64; off <<= 1) {
        int t = __shfl_up(incl, off);
        if (lane >= off) incl += t;
    }
    __shared__ int wsum[4];
    if (lane == 63) wsum[wave] = incl;
    __syncthreads();
    int wbase = 0;
    for (int w = 0; w < 4; w++) wbase += (w < wave) ? wsum[w] : 0;

    int run = incl - s + wbase + blockSums[blockIdx.x];
    #pragma unroll
    for (int j = 0; j < 8; j++) {
        int idx = i0 + j;
        if (idx < n) { offsets[idx] = run; cursor[idx] = run; }
        run += vals[j];
    }
}

__global__ __launch_bounds__(256) void fill_kernel(
    const int* __restrict__ p2v, int* __restrict__ cursor,
    int* __restrict__ plist, int n)
{
    int i = blockIdx.x * blockDim.x + threadIdx.x;
    if (i < n) {
        int v = p2v[i];
        int pos = atomicAdd(&cursor[v], 1);
        plist[pos] = i;
    }
}

__global__ __launch_bounds__(256) void fuse_kernel(
    const float* __restrict__ p_feats, const float* __restrict__ v_feats,
    const float* __restrict__ Wp, const float* __restrict__ bp,
    const float* __restrict__ Wv, const float* __restrict__ bv,
    const int* __restrict__ p2v,
    float* __restrict__ fuse_out, int n_pts)
{
    const int t = threadIdx.x & 15;  // 16 threads/point, 4 channels each

    const float4* Wp4 = (const float4*)Wp;
    const float4* Wv4 = (const float4*)Wv;
    const float4 wpA = Wp4[2 * t], wpB = Wp4[2 * t + 1];
    const float4 wvA = Wv4[2 * t], wvB = Wv4[2 * t + 1];
    const float bias0 = bp[0] + bv[0];
    const float bias1 = bp[1] + bv[1];

    const int gid = blockIdx.x * blockDim.x + threadIdx.x;
    const int stride = (gridDim.x * blockDim.x) >> 4;

    for (int pt = gid >> 4; pt < n_pts; pt += stride) {
        const int vox = p2v[pt];
        const float4 pf = *(const float4*)(p_feats + (size_t)pt * C + t * 4);
        const float4 vf = *(const float4*)(v_feats + (size_t)vox * C + t * 4);

        float l0 = pf.x * wpA.x + pf.y * wpA.z + pf.z * wpB.x + pf.w * wpB.z
                 + vf.x * wvA.x + vf.y * wvA.z + vf.z * wvB.x + vf.w * wvB.z;
        float l1 = pf.x * wpA.y + pf.y * wpA.w + pf.z * wpB.y + pf.w * wpB.w
                 + vf.x * wvA.y + vf.y * wvA.w + vf.z * wvB.y + vf.w * wvB.w;

        #pragma unroll
        for (int m = 1; m < 16; m <<= 1) {
            l0 += __shfl_xor(l0, m);
            l1 += __shfl_xor(l1, m);
        }
        l0 += bias0;
        l1 += bias1;

        const float mx = fmaxf(l0, l1);
        const float e0 = __expf(l0 - mx), e1 = __expf(l1 - mx);
        const float w0 = e0 / (e0 + e1);
        const float w1 = 1.0f - w0;

        float4 f;
        f.x = pf.x * w0 + vf.x * w1;
        f.y = pf.y * w0 + vf.y * w1;
        f.z = pf.z * w0 + vf.z * w1;
        f.w = pf.w * w0 + vf.w * w1;

        *(float4*)(fuse_out + (size_t)pt * C + t * 4) = f;
    }
}

__global__ __launch_bounds__(256) void gather_kernel(
    const float* __restrict__ fuse, const int* __restrict__ offsets,
    const int* __restrict__ plist, float* __restrict__ v_new, int n_vox)
{
    const int gid = blockIdx.x * blockDim.x + threadIdx.x;
    const int v = gid >> 4;
    const int t = gid & 15;
    if (v >= n_vox) return;

    const int beg = offsets[v], end = offsets[v + 1];
    float4 acc = make_float4(0.f, 0.f, 0.f, 0.f);
    for (int i = beg; i < end; i++) {
        const int p = plist[i];
        const float4 f = *(const float4*)(fuse + (size_t)p * C + t * 4);
        acc.x += f.x; acc.y += f.y; acc.z += f.z; acc.w += f.w;
    }
    const float inv = 1.0f / (float)max(end - beg, 1);
    float4 r;
    r.x = acc.x * inv; r.y = acc.y * inv; r.z = acc.z * inv; r.w = acc.w * inv;
    *(float4*)(v_new + (size_t)v * C + t * 4) = r;
}

extern "C" void kernel_launch(void* const* d_in, const int* in_sizes, int n_in,
                              void* d_out, int out_size, void* d_ws, size_t ws_size,
                              hipStream_t stream) {
    const float* p_feats = (const float*)d_in[0];
    const float* v_feats = (const float*)d_in[1];
    const float* Wp = (const float*)d_in[2];
    const float* bp = (const float*)d_in[3];
    const float* Wv = (const float*)d_in[4];
    const float* bv = (const float*)d_in[5];
    const int* p2v = (const int*)d_in[6];

    const int n_pts = in_sizes[0] / C;
    const int n_vox = in_sizes[1] / C;

    float* fuse_out = (float*)d_out;
    float* v_new = fuse_out + (size_t)n_pts * C;

    // workspace layout
    int* offsets = (int*)d_ws;                        // n_vox+1
    int* counts = offsets + (n_vox + 1);              // n_vox (reused as cursor)
    int* blockSums = counts + n_vox;                  // 256
    int* plist = blockSums + 256;                     // n_pts

    const int nb = (n_vox + SCAN_ELEMS - 1) / SCAN_ELEMS;

    hipMemsetAsync(counts, 0, (size_t)n_vox * sizeof(int), stream);

    const int T = 256;
    hist_kernel<<<(n_pts + T - 1) / T, T, 0, stream>>>(p2v, counts, n_pts);
    scan1_kernel<<<nb, T, 0, stream>>>(counts, blockSums, n_vox);
    scan2_kernel<<<1, T, 0, stream>>>(blockSums, offsets, nb, n_vox);
    scan3_kernel<<<nb, T, 0, stream>>>(counts, blockSums, offsets, counts, n_vox);
    fill_kernel<<<(n_pts + T - 1) / T, T, 0, stream>>>(p2v, counts, plist, n_pts);

    fuse_kernel<<<8192, T, 0, stream>>>(
        p_feats, v_feats, Wp, bp, Wv, bv, p2v, fuse_out, n_pts);

    gather_kernel<<<(n_vox * 16 + T - 1) / T, T, 0, stream>>>(
        fuse_out, offsets, plist, v_new, n_vox);
}

// Round 3
// 545.319 us; speedup vs baseline: 3.4220x; 1.2314x over previous
//
#include <hip/hip_runtime.h>

#define C 64

// ---------------------------------------------------------------------------
// CSR build (no float atomics), then ONE fused voxel-centric pass:
//  1. memset counts
//  2. hist:   counts[v]++ per point           (int atomics, L2-resident)
//  3. scan1:  per-block (2048) reduce -> blockSums
//  4. scan2:  single-block scan of blockSums (nb<=256), offsets[n_vox]=total
//  5. scan3:  per-block exclusive scan -> offsets; cursor=offsets
//  6. fill:   plist[atomicAdd(cursor[v])] = point_id
//  7. fused:  per voxel (16 threads): read v_feats row once, loop its points:
//             read p_feats row, gate MLP + softmax, write fuse row,
//             accumulate -> write v_new = acc/max(count,1).
// ---------------------------------------------------------------------------

static const int SCAN_ELEMS = 2048;   // 256 threads x 8

__global__ __launch_bounds__(256) void hist_kernel(
    const int* __restrict__ p2v, int* __restrict__ counts, int n)
{
    int i = blockIdx.x * blockDim.x + threadIdx.x;
    if (i < n) atomicAdd(&counts[p2v[i]], 1);
}

__global__ __launch_bounds__(256) void scan1_kernel(
    const int* __restrict__ counts, int* __restrict__ blockSums, int n)
{
    const int base = blockIdx.x * SCAN_ELEMS;
    const int tid = threadIdx.x;
    int s = 0;
    const int i0 = base + tid * 8;
    #pragma unroll
    for (int j = 0; j < 8; j++) {
        int idx = i0 + j;
        s += (idx < n) ? counts[idx] : 0;
    }
    #pragma unroll
    for (int m = 1; m < 64; m <<= 1) s += __shfl_xor(s, m);
    __shared__ int wsum[4];
    const int lane = tid & 63, wave = tid >> 6;
    if (lane == 0) wsum[wave] = s;
    __syncthreads();
    if (tid == 0) blockSums[blockIdx.x] = wsum[0] + wsum[1] + wsum[2] + wsum[3];
}

__global__ __launch_bounds__(256) void scan2_kernel(
    int* __restrict__ blockSums, int* __restrict__ offsets, int nb, int n_vox)
{
    __shared__ int sh[256];
    const int tid = threadIdx.x;
    const int v = (tid < nb) ? blockSums[tid] : 0;
    sh[tid] = v;
    __syncthreads();
    #pragma unroll
    for (int off = 1; off < 256; off <<= 1) {
        int t = (tid >= off) ? sh[tid - off] : 0;
        __syncthreads();
        sh[tid] += t;
        __syncthreads();
    }
    if (tid < nb) blockSums[tid] = sh[tid] - v;   // exclusive
    if (tid == 255) offsets[n_vox] = sh[255];     // total = n_pts
}

__global__ __launch_bounds__(256) void scan3_kernel(
    const int* __restrict__ counts, const int* __restrict__ blockSums,
    int* __restrict__ offsets, int* __restrict__ cursor, int n)
{
    const int base = blockIdx.x * SCAN_ELEMS;
    const int tid = threadIdx.x;
    const int i0 = base + tid * 8;
    int vals[8];
    #pragma unroll
    for (int j = 0; j < 8; j++) {
        int idx = i0 + j;
        vals[j] = (idx < n) ? counts[idx] : 0;
    }
    int s = 0;
    #pragma unroll
    for (int j = 0; j < 8; j++) s += vals[j];

    const int lane = tid & 63, wave = tid >> 6;
    int incl = s;
    #pragma unroll
    for (int off = 1; off < 64; off <<= 1) {
        int t = __shfl_up(incl, off);
        if (lane >= off) incl += t;
    }
    __shared__ int wsum[4];
    if (lane == 63) wsum[wave] = incl;
    __syncthreads();
    int wbase = 0;
    for (int w = 0; w < 4; w++) wbase += (w < wave) ? wsum[w] : 0;

    int run = incl - s + wbase + blockSums[blockIdx.x];
    #pragma unroll
    for (int j = 0; j < 8; j++) {
        int idx = i0 + j;
        if (idx < n) { offsets[idx] = run; cursor[idx] = run; }
        run += vals[j];
    }
}

__global__ __launch_bounds__(256) void fill_kernel(
    const int* __restrict__ p2v, int* __restrict__ cursor,
    int* __restrict__ plist, int n)
{
    int i = blockIdx.x * blockDim.x + threadIdx.x;
    if (i < n) {
        int v = p2v[i];
        int pos = atomicAdd(&cursor[v], 1);
        plist[pos] = i;
    }
}

__global__ __launch_bounds__(256) void fused_kernel(
    const float* __restrict__ p_feats, const float* __restrict__ v_feats,
    const float* __restrict__ Wp, const float* __restrict__ bp,
    const float* __restrict__ Wv, const float* __restrict__ bv,
    const int* __restrict__ offsets, const int* __restrict__ plist,
    float* __restrict__ fuse_out, float* __restrict__ v_new, int n_vox)
{
    const int gid = blockIdx.x * blockDim.x + threadIdx.x;
    const int v = gid >> 4;          // 16 threads per voxel
    const int t = gid & 15;          // 4 channels per thread
    if (v >= n_vox) return;

    // Wp/Wv are [C,2] row-major; thread t needs rows 4t..4t+3 => two float4s
    const float4* Wp4 = (const float4*)Wp;
    const float4* Wv4 = (const float4*)Wv;
    const float4 wpA = Wp4[2 * t], wpB = Wp4[2 * t + 1];
    const float4 wvA = Wv4[2 * t], wvB = Wv4[2 * t + 1];
    const float bias0 = bp[0] + bv[0];
    const float bias1 = bp[1] + bv[1];

    // voxel feature row: read once, reuse for all its points
    const float4 vf = *(const float4*)(v_feats + (size_t)v * C + t * 4);

    // v-side logit contribution (computed once per voxel)
    float lv0 = vf.x * wvA.x + vf.y * wvA.z + vf.z * wvB.x + vf.w * wvB.z;
    float lv1 = vf.x * wvA.y + vf.y * wvA.w + vf.z * wvB.y + vf.w * wvB.w;
    #pragma unroll
    for (int m = 1; m < 16; m <<= 1) {
        lv0 += __shfl_xor(lv0, m);
        lv1 += __shfl_xor(lv1, m);
    }
    lv0 += bias0;
    lv1 += bias1;

    const int beg = offsets[v], end = offsets[v + 1];
    float4 acc = make_float4(0.f, 0.f, 0.f, 0.f);

    for (int i = beg; i < end; i++) {
        const int p = plist[i];
        const float4 pf = *(const float4*)(p_feats + (size_t)p * C + t * 4);

        float l0 = pf.x * wpA.x + pf.y * wpA.z + pf.z * wpB.x + pf.w * wpB.z;
        float l1 = pf.x * wpA.y + pf.y * wpA.w + pf.z * wpB.y + pf.w * wpB.w;
        #pragma unroll
        for (int m = 1; m < 16; m <<= 1) {
            l0 += __shfl_xor(l0, m);
            l1 += __shfl_xor(l1, m);
        }
        l0 += lv0;
        l1 += lv1;

        const float mx = fmaxf(l0, l1);
        const float e0 = __expf(l0 - mx), e1 = __expf(l1 - mx);
        const float w0 = e0 / (e0 + e1);
        const float w1 = 1.0f - w0;

        float4 f;
        f.x = pf.x * w0 + vf.x * w1;
        f.y = pf.y * w0 + vf.y * w1;
        f.z = pf.z * w0 + vf.z * w1;
        f.w = pf.w * w0 + vf.w * w1;

        *(float4*)(fuse_out + (size_t)p * C + t * 4) = f;
        acc.x += f.x; acc.y += f.y; acc.z += f.z; acc.w += f.w;
    }

    const float inv = 1.0f / (float)max(end - beg, 1);
    float4 r;
    r.x = acc.x * inv; r.y = acc.y * inv; r.z = acc.z * inv; r.w = acc.w * inv;
    *(float4*)(v_new + (size_t)v * C + t * 4) = r;
}

extern "C" void kernel_launch(void* const* d_in, const int* in_sizes, int n_in,
                              void* d_out, int out_size, void* d_ws, size_t ws_size,
                              hipStream_t stream) {
    const float* p_feats = (const float*)d_in[0];
    const float* v_feats = (const float*)d_in[1];
    const float* Wp = (const float*)d_in[2];
    const float* bp = (const float*)d_in[3];
    const float* Wv = (const float*)d_in[4];
    const float* bv = (const float*)d_in[5];
    const int* p2v = (const int*)d_in[6];

    const int n_pts = in_sizes[0] / C;
    const int n_vox = in_sizes[1] / C;

    float* fuse_out = (float*)d_out;
    float* v_new = fuse_out + (size_t)n_pts * C;

    // workspace layout (ints)
    int* offsets = (int*)d_ws;                        // n_vox+1
    int* counts = offsets + (n_vox + 1);              // n_vox (reused as cursor)
    int* blockSums = counts + n_vox;                  // 256
    int* plist = blockSums + 256;                     // n_pts

    const int nb = (n_vox + SCAN_ELEMS - 1) / SCAN_ELEMS;
    const int T = 256;

    hipMemsetAsync(counts, 0, (size_t)n_vox * sizeof(int), stream);
    hist_kernel<<<(n_pts + T - 1) / T, T, 0, stream>>>(p2v, counts, n_pts);
    scan1_kernel<<<nb, T, 0, stream>>>(counts, blockSums, n_vox);
    scan2_kernel<<<1, T, 0, stream>>>(blockSums, offsets, nb, n_vox);
    scan3_kernel<<<nb, T, 0, stream>>>(counts, blockSums, offsets, counts, n_vox);
    fill_kernel<<<(n_pts + T - 1) / T, T, 0, stream>>>(p2v, counts, plist, n_pts);

    fused_kernel<<<(n_vox * 16 + T - 1) / T, T, 0, stream>>>(
        p_feats, v_feats, Wp, bp, Wv, bv, offsets, plist,
        fuse_out, v_new, n_vox);
}